// Round 2
// baseline (990.070 us; speedup 1.0000x reference)
//
#include <hip/hip_runtime.h>
#include <hip/hip_bf16.h>

typedef unsigned long long u64;

#define KNMS 1000      // MAX_BOX_PRE_NMS (hardcoded in reference)
#define KP   1024      // padded stride for per-pair arrays
#define CAP  4096      // candidate capacity per pair
#define NBIN 8192      // radix-select histogram bins (score bits >> 18)
#define SLC  8         // A-dimension splits for hist/compact
#define FBN  8192      // final per-batch sort size (>= C*mb)
#define IOU_THR 0.5f

#define NEGINF __uint_as_float(0xFF800000u)

// ---------------------------------------------------------------------------
// helpers
// ---------------------------------------------------------------------------

// Find the histogram bin containing rank `rank` counting from the TOP.
__device__ __forceinline__ void find_cutoff(unsigned int* hist, int nbins,
    unsigned int* csum, int nthreads, int tid, unsigned int rank,
    unsigned int* s_bin, unsigned int* s_gt, unsigned int* s_total, int* s_all) {
  int chunk = nbins / nthreads;
  unsigned int cs = 0;
  int base = tid * chunk;
  for (int q = 0; q < chunk; q++) cs += hist[base + q];
  csum[tid] = cs;
  __syncthreads();
  if (tid == 0) {
    unsigned int total = 0;
    for (int ch = 0; ch < nthreads; ch++) total += csum[ch];
    *s_total = total;
    if (total <= rank) { *s_bin = 0u; *s_gt = 0u; *s_all = 1; }
    else {
      unsigned int acc = 0; int ch = nthreads - 1;
      while (acc + csum[ch] < rank) { acc += csum[ch]; ch--; }
      int bin = ch * chunk + chunk - 1;
      while (acc + hist[bin] < rank) { acc += hist[bin]; bin--; }
      *s_bin = (unsigned)bin; *s_gt = acc; *s_all = 0;
    }
  }
  __syncthreads();
}

// In-LDS bitonic sort, descending, 64-bit keys.
template<int N, int NT>
__device__ __forceinline__ void bitonic_desc(u64* a, int tid) {
  for (int k = 2; k <= N; k <<= 1) {
    for (int j = k >> 1; j > 0; j >>= 1) {
      for (int t = tid; t < N; t += NT) {
        int ixj = t ^ j;
        if (ixj > t) {
          u64 x = a[t], y = a[ixj];
          if (((t & k) == 0) ? (x < y) : (x > y)) { a[t] = y; a[ixj] = x; }
        }
      }
      __syncthreads();
    }
  }
}

// ---------------------------------------------------------------------------
// kernel 1: transpose classification [B,A,C] -> [B,C,A]  (C <= 127)
// ---------------------------------------------------------------------------
__global__ __launch_bounds__(256) void k_transpose(const float* __restrict__ src0,
    float* __restrict__ dst0, int A, int C) {
  __shared__ float tile[64 * 129];
  int b = blockIdx.y;
  int a0 = blockIdx.x * 64;
  const float* src = src0 + (size_t)b * A * C;
  float* dst = dst0 + (size_t)b * A * C;
  int st = C + 1;
  for (int idx = threadIdx.x; idx < 64 * C; idx += 256) {
    int al = idx / C, c = idx - al * C;
    int a = a0 + al;
    tile[al * st + c] = (a < A) ? src[(size_t)a * C + c] : 0.f;
  }
  __syncthreads();
  for (int idx = threadIdx.x; idx < 64 * C; idx += 256) {
    int c = idx >> 6, al = idx & 63;
    int a = a0 + al;
    if (a < A) dst[(size_t)c * A + a] = tile[al * st + c];
  }
}

// ---------------------------------------------------------------------------
// kernel 2a: per (pair, slice): LDS histogram of score bits>>18, merged to
// global hist via atomics (only ~32 nonzero bins/block -> cheap).
// ---------------------------------------------------------------------------
__global__ __launch_bounds__(256) void k_hist(const float* __restrict__ cls,
    int transposed, const float* __restrict__ thr_p,
    unsigned int* __restrict__ ghist, int A, int C) {
  int pair = blockIdx.x, s = blockIdx.y, tid = threadIdx.x;
  int b = pair / C, c = pair - b * C;
  const float* col; int str;
  if (transposed) { col = cls + (size_t)pair * A; str = 1; }
  else            { col = cls + (size_t)b * A * C + c; str = C; }
  float thr = *thr_p;
  __shared__ unsigned int lh[NBIN];
  for (int i = tid; i < NBIN; i += 256) lh[i] = 0u;
  __syncthreads();
  bool vec = (str == 1) && ((A & 3) == 0);
  if (vec) {
    const float4* col4 = (const float4*)col;
    int A4 = A >> 2;
    int n4 = (A4 + SLC - 1) / SLC, i0 = s * n4, i1 = min(A4, i0 + n4);
    for (int i = i0 + tid; i < i1; i += 256) {
      float4 v = col4[i];
      float vv[4] = {v.x, v.y, v.z, v.w};
#pragma unroll
      for (int q = 0; q < 4; q++)
        if (vv[q] > thr) atomicAdd(&lh[__float_as_uint(vv[q]) >> 18], 1u);
    }
  } else {
    int nE = (A + SLC - 1) / SLC, a0 = s * nE, a1 = min(A, a0 + nE);
    for (int a = a0 + tid; a < a1; a += 256) {
      float sv = col[(size_t)a * str];
      if (sv > thr) atomicAdd(&lh[__float_as_uint(sv) >> 18], 1u);
    }
  }
  __syncthreads();
  unsigned int* gh = ghist + (size_t)pair * NBIN;
  for (int i = tid; i < NBIN; i += 256) {
    unsigned v = lh[i];
    if (v) atomicAdd(&gh[i], v);
  }
}

// ---------------------------------------------------------------------------
// kernel 2b: per pair: find cutoff bin for rank KNMS. cut=0 means take-all.
// Margin note: with bin width 2^-18 of score-bit space, boundary-bin count
// for this workload is ~1.6K; takers <= ~2.6K << CAP=4096.
// ---------------------------------------------------------------------------
__global__ __launch_bounds__(512) void k_cutoff(const unsigned int* __restrict__ ghist,
    unsigned int* __restrict__ cut) {
  int pair = blockIdx.x, tid = threadIdx.x;
  __shared__ unsigned int lh[NBIN];
  __shared__ unsigned int csum[512];
  __shared__ unsigned int s_b1, s_gt, s_tot;
  __shared__ int s_all;
  const unsigned int* gh = ghist + (size_t)pair * NBIN;
  for (int i = tid; i < NBIN; i += 512) lh[i] = gh[i];
  __syncthreads();
  find_cutoff(lh, NBIN, csum, 512, tid, KNMS, &s_b1, &s_gt, &s_tot, &s_all);
  if (tid == 0) cut[pair] = s_all ? 0u : s_b1;
}

// ---------------------------------------------------------------------------
// kernel 2c: per (pair, slice): compact keys of elements with bin >= cut into
// per-pair global buffer. Wave-aggregated counter atomics.
// key = (score_bits << 32) | ~anchor_index (stable: low index wins ties)
// ---------------------------------------------------------------------------
__device__ __forceinline__ void emit(u64 key, bool take, int pair,
    int* __restrict__ gcnt, u64* __restrict__ gcand) {
  u64 m = __ballot(take);
  if (!m) return;
  int lane = threadIdx.x & 63;
  int ldr = __ffsll((long long)m) - 1;
  int base = 0;
  if (lane == ldr) base = atomicAdd(&gcnt[pair], (int)__popcll(m));
  base = __shfl(base, ldr);
  if (take) {
    int pos = base + (int)__popcll(m & ((1ull << lane) - 1ull));
    if (pos < CAP) gcand[(size_t)pair * CAP + pos] = key;
  }
}

__global__ __launch_bounds__(256) void k_compact(const float* __restrict__ cls,
    int transposed, const float* __restrict__ thr_p,
    const unsigned int* __restrict__ cut, int* __restrict__ gcnt,
    u64* __restrict__ gcand, int A, int C) {
  int pair = blockIdx.x, s = blockIdx.y, tid = threadIdx.x;
  int b = pair / C, c = pair - b * C;
  const float* col; int str;
  if (transposed) { col = cls + (size_t)pair * A; str = 1; }
  else            { col = cls + (size_t)b * A * C + c; str = C; }
  float thr = *thr_p;
  unsigned b1 = cut[pair];
  bool vec = (str == 1) && ((A & 3) == 0);
  if (vec) {
    const float4* col4 = (const float4*)col;
    int A4 = A >> 2;
    int n4 = (A4 + SLC - 1) / SLC, i0 = s * n4, i1 = min(A4, i0 + n4);
    for (int i = i0 + tid; i < i1; i += 256) {
      float4 v = col4[i];
      float vv[4] = {v.x, v.y, v.z, v.w};
#pragma unroll
      for (int q = 0; q < 4; q++) {
        float sv = vv[q];
        unsigned bits = __float_as_uint(sv);
        bool take = (sv > thr) && ((bits >> 18) >= b1);
        u64 key = ((u64)bits << 32) | (unsigned)(~(unsigned)(i * 4 + q));
        emit(key, take, pair, gcnt, gcand);
      }
    }
  } else {
    int nE = (A + SLC - 1) / SLC, a0 = s * nE, a1 = min(A, a0 + nE);
    for (int a = a0 + tid; a < a1; a += 256) {
      float sv = col[(size_t)a * str];
      unsigned bits = __float_as_uint(sv);
      bool take = (sv > thr) && ((bits >> 18) >= b1);
      u64 key = ((u64)bits << 32) | (unsigned)(~(unsigned)a);
      emit(key, take, pair, gcnt, gcand);
    }
  }
}

// ---------------------------------------------------------------------------
// kernel 2d: per pair: sort candidates desc, gather boxes, write sorted arrays
// ---------------------------------------------------------------------------
__global__ __launch_bounds__(1024) void k_sortpairs(const u64* __restrict__ gcand,
    const int* __restrict__ gcnt, const float* __restrict__ tanch,
    float* __restrict__ scores_s, float* __restrict__ boxes_s,
    float* __restrict__ area_s, int* __restrict__ cnt_s, int A, int C) {
  int pair = blockIdx.x, tid = threadIdx.x;
  int b = pair / C;
  __shared__ u64 cand[CAP];
  int nc = gcnt[pair];
  int n = nc < CAP ? nc : CAP;
  for (int t = tid; t < CAP; t += 1024)
    cand[t] = (t < n) ? gcand[(size_t)pair * CAP + t] : 0ull;
  __syncthreads();
  bitonic_desc<CAP, 1024>(cand, tid);
  int n_valid = nc < KNMS ? nc : KNMS;
  for (int k = tid; k < KNMS; k += 1024) {
    u64 key = cand[k];
    float sc; float4 bx; float ar;
    if (k < n_valid && key != 0ull) {
      sc = __uint_as_float((unsigned)(key >> 32));
      unsigned a = ~(unsigned)key;
      bx = ((const float4*)tanch)[(size_t)b * A + a];
      ar = (bx.z - bx.x) * (bx.w - bx.y);
    } else {
      sc = NEGINF; bx = make_float4(0.f, 0.f, 0.f, 0.f); ar = 0.f;
    }
    scores_s[(size_t)pair * KP + k] = sc;
    ((float4*)boxes_s)[(size_t)pair * KP + k] = bx;
    area_s[(size_t)pair * KP + k] = ar;
  }
  if (tid == 0) cnt_s[pair] = n_valid;
}

// ---------------------------------------------------------------------------
// kernel 3: suppression matrix. Bit-exact vs reference:
// fl(inter/uni) > 0.5  <=>  2*inter > uni*(1+2^-24), exact in f64
// (24-bit x 25-bit mantissas fit 53 bits; midpoint ties round to even 0.5;
//  inter=uni=0 -> NaN -> false on both sides; uni<0 impossible).
// ---------------------------------------------------------------------------
__global__ __launch_bounds__(256) void k_iou(const float* __restrict__ boxes_s,
    const float* __restrict__ area_s, const int* __restrict__ cnt_s,
    u64* __restrict__ mat) {
  int pair = blockIdx.x, w = blockIdx.y;
  int cnt = cnt_s[pair];
  int lim = (w + 1) * 64; if (lim > KNMS) lim = KNMS;  // rows needed: i < w*64+63
  __shared__ float4 sbox[KNMS];
  __shared__ float sarea[KNMS];
  for (int i = threadIdx.x; i < lim; i += 256) {
    sbox[i] = ((const float4*)boxes_s)[(size_t)pair * KP + i];
    sarea[i] = area_s[(size_t)pair * KP + i];
  }
  __syncthreads();
  int lane = threadIdx.x & 63, wv = threadIdx.x >> 6;
  int j = w * 64 + lane;
  bool jok = j < KNMS;
  float4 bj = (jok && j < lim) ? sbox[j] : make_float4(0.f, 0.f, 0.f, 0.f);
  float aj = (jok && j < lim) ? sarea[j] : 0.f;
  u64* orow = mat + (size_t)pair * KP * 16 + w;
  int rowLim = cnt < (w * 64 + 63) ? cnt : (w * 64 + 63);
  for (int i = wv; i < rowLim; i += 4) {
    float4 bi = sbox[i]; float ai = sarea[i];
    float ltx = fmaxf(bi.x, bj.x), lty = fmaxf(bi.y, bj.y);
    float rbx = fminf(bi.z, bj.z), rby = fminf(bi.w, bj.w);
    float ww = fmaxf(rbx - ltx, 0.f), hh = fmaxf(rby - lty, 0.f);
    float inter = ww * hh;
    float uni = (ai + aj) - inter;
    bool sup = jok && (j > i) &&
               ((double)inter * 2.0 > (double)uni * (1.0 + 0x1p-24));
    u64 word = __ballot(sup);
    if (lane == 0) orow[(size_t)i * 16] = word;
  }
  for (int i = rowLim + wv; i < cnt; i += 4)
    if (lane == 0) orow[(size_t)i * 16] = 0ull;
}

// ---------------------------------------------------------------------------
// kernel 4: serial greedy scan. 1 wave per pair; lanes 0..15 own keep-words.
// ---------------------------------------------------------------------------
__global__ __launch_bounds__(64) void k_scan(const u64* __restrict__ mat,
    const int* __restrict__ cnt_s, u64* __restrict__ keep_out) {
  int pair = blockIdx.x;
  int lane = threadIdx.x;
  int cnt = cnt_s[pair];
  const u64* m = mat + (size_t)pair * KP * 16;
  u64 keepw = 0ull;
  if (lane < 16) {
    int nb = cnt - lane * 64;
    nb = nb < 0 ? 0 : (nb > 64 ? 64 : nb);
    keepw = (nb >= 64) ? ~0ull : ((nb > 0) ? ((1ull << nb) - 1ull) : 0ull);
  }
  bool ld = lane < 16;
  u64 cur[16], nxt[16];
#pragma unroll
  for (int r = 0; r < 16; r++) cur[r] = (ld && r < cnt) ? m[(size_t)r * 16 + lane] : 0ull;
  for (int g = 0; g < cnt; g += 16) {
#pragma unroll
    for (int r = 0; r < 16; r++) {
      int i = g + 16 + r;
      nxt[r] = (ld && i < cnt) ? m[(size_t)i * 16 + lane] : 0ull;
    }
#pragma unroll
    for (int r = 0; r < 16; r++) {
      int i = g + r;
      if (i < cnt) {
        u64 kw = __shfl(keepw, i >> 6);
        if ((kw >> (i & 63)) & 1ull) keepw &= ~cur[r];
      }
      cur[r] = nxt[r];
    }
  }
  if (lane < 16) keep_out[pair * 16 + lane] = keepw;
}

// ---------------------------------------------------------------------------
// kernel 5a: per pair: emit top-min(mb,kept) kept keys (scores_s is sorted,
// so the first set bits ARE the best). 1 wave per pair.
// key = (score_bits << 32) | ~(c*KNMS + k)
// ---------------------------------------------------------------------------
__global__ __launch_bounds__(64) void k_fa(const u64* __restrict__ keepm,
    const float* __restrict__ scores_s, u64* __restrict__ fa, int C, int mb) {
  int pair = blockIdx.x;
  int lane = threadIdx.x;
  int c = pair % C;
  u64 kw = (lane < 16) ? keepm[pair * 16 + lane] : 0ull;
  int pc = __popcll(kw);
  int scan = pc;
  for (int d = 1; d < 16; d <<= 1) {
    int o = __shfl_up(scan, d);
    if (lane >= d) scan += o;
  }
  int base = scan - pc;
  int total = __shfl(scan, 15);
  if (lane < 16) {
    u64 m = kw; int r = base;
    while (m && r < mb) {
      int bit = __ffsll((long long)m) - 1; m &= m - 1;
      int k = lane * 64 + bit;
      float s = scores_s[(size_t)pair * KP + k];
      fa[(size_t)pair * mb + r] =
          ((u64)__float_as_uint(s) << 32) | (unsigned)(~(unsigned)(c * KNMS + k));
      r++;
    }
  }
  int start = total < mb ? total : mb;
  for (int r = start + lane; r < mb; r += 64) fa[(size_t)pair * mb + r] = 0ull;
}

// ---------------------------------------------------------------------------
// kernel 5b: per batch: sort C*mb candidate keys desc, write outputs.
// ---------------------------------------------------------------------------
__global__ __launch_bounds__(1024) void k_fb(const u64* __restrict__ fa,
    const float* __restrict__ boxes_s, float* __restrict__ out,
    int B, int C, int mb) {
  int b = blockIdx.x, tid = threadIdx.x;
  __shared__ u64 cand[FBN];
  int nk = C * mb; if (nk > FBN) nk = FBN;
  const u64* src = fa + (size_t)b * C * mb;
  for (int i = tid; i < FBN; i += 1024) cand[i] = (i < nk) ? src[i] : 0ull;
  __syncthreads();
  bitonic_desc<FBN, 1024>(cand, tid);
  for (int k = tid; k < mb; k += 1024) {
    u64 key = cand[k];
    float4 bx = make_float4(0.f, 0.f, 0.f, 0.f);
    float sc = 0.f, cf = -1.f;
    if (key != 0ull) {
      sc = __uint_as_float((unsigned)(key >> 32));
      unsigned flat = ~(unsigned)key;
      int c = flat / KNMS;
      int kk = flat - c * KNMS;
      bx = ((const float4*)boxes_s)[(size_t)(b * C + c) * KP + kk];
      cf = (float)c;
    }
    size_t ro = (size_t)(b * mb + k) * 4;
    out[ro + 0] = bx.x; out[ro + 1] = bx.y; out[ro + 2] = bx.z; out[ro + 3] = bx.w;
    out[(size_t)B * mb * 4 + b * mb + k] = sc;
    out[(size_t)B * mb * 5 + b * mb + k] = cf;
  }
}

// ---------------------------------------------------------------------------
extern "C" void kernel_launch(void* const* d_in, const int* in_sizes, int n_in,
                              void* d_out, int out_size, void* d_ws, size_t ws_size,
                              hipStream_t stream) {
  const float* classification = (const float*)d_in[3];
  const float* tanch = (const float*)d_in[4];
  const float* thr_p = (const float*)d_in[5];

  int B = in_sizes[0] / (3 * 64 * 64);
  if (B <= 0) B = 4;
  long long BA = (long long)in_sizes[4] / 4;
  int A = (int)(BA / B);
  int C = (int)((long long)in_sizes[3] / BA);
  int NP = B * C;
  int mb = out_size / (B * 6);

  auto rsz = [](size_t x) { return (x + 255) & ~(size_t)255; };
  size_t clsT_bytes = rsz((size_t)NP * A * 4);
  size_t rest = rsz((size_t)NP * KP * 4)       // scores
              + rsz((size_t)NP * KP * 16)      // boxes
              + rsz((size_t)NP * KP * 4)       // areas
              + rsz((size_t)NP * 4)            // counts
              + rsz((size_t)NP * KP * 16 * 8)  // suppression matrix (+aliases)
              + rsz((size_t)NP * 16 * 8);      // keep masks
  int use_t = (C <= 127 && ws_size >= rest + clsT_bytes) ? 1 : 0;

  size_t off = 0;
  auto take = [&](size_t bytes) {
    void* p = (char*)d_ws + off;
    off += rsz(bytes);
    return p;
  };
  float* clsT = nullptr;
  if (use_t) clsT = (float*)take((size_t)NP * A * 4);
  float* scores_s = (float*)take((size_t)NP * KP * 4);
  float* boxes_s  = (float*)take((size_t)NP * KP * 16);
  float* area_s   = (float*)take((size_t)NP * KP * 4);
  int*   cnt_s    = (int*)take((size_t)NP * 4);
  u64*   mat      = (u64*)take((size_t)NP * KP * 16 * 8);
  u64*   keepm    = (u64*)take((size_t)NP * 16 * 8);

  // Alias selection/final scratch into the mat region (disjoint lifetimes:
  // ghist/gcnt/cut/gcand die before k_iou writes mat; fa is written after
  // k_scan's last read of mat). Total aliased ~21.2 MB <= 41.9 MB.
  char* matc = (char*)mat;
  size_t ao = 0;
  unsigned int* ghist = (unsigned int*)(matc + ao); ao += rsz((size_t)NP * NBIN * 4);
  int* gcnt           = (int*)(matc + ao);          ao += rsz((size_t)NP * 4);
  unsigned int* cut   = (unsigned int*)(matc + ao); ao += rsz((size_t)NP * 4);
  u64* gcand          = (u64*)(matc + ao);          ao += rsz((size_t)NP * CAP * 8);
  u64* fa             = (u64*)(matc + ao);          ao += rsz((size_t)NP * mb * 8);

  hipMemsetAsync(ghist, 0, (size_t)NP * NBIN * 4, stream);
  hipMemsetAsync(gcnt, 0, (size_t)NP * 4, stream);

  if (use_t)
    k_transpose<<<dim3((A + 63) / 64, B), 256, 0, stream>>>(classification, clsT, A, C);
  const float* cl = use_t ? clsT : classification;
  k_hist<<<dim3(NP, SLC), 256, 0, stream>>>(cl, use_t, thr_p, ghist, A, C);
  k_cutoff<<<NP, 512, 0, stream>>>(ghist, cut);
  k_compact<<<dim3(NP, SLC), 256, 0, stream>>>(cl, use_t, thr_p, cut, gcnt, gcand, A, C);
  k_sortpairs<<<NP, 1024, 0, stream>>>(gcand, gcnt, tanch, scores_s, boxes_s, area_s, cnt_s, A, C);
  k_iou<<<dim3(NP, 16), 256, 0, stream>>>(boxes_s, area_s, cnt_s, mat);
  k_scan<<<NP, 64, 0, stream>>>(mat, cnt_s, keepm);
  k_fa<<<NP, 64, 0, stream>>>(keepm, scores_s, fa, C, mb);
  k_fb<<<B, 1024, 0, stream>>>(fa, boxes_s, (float*)d_out, B, C, mb);
}

// Round 3
// 698.805 us; speedup vs baseline: 1.4168x; 1.4168x over previous
//
#include <hip/hip_runtime.h>
#include <hip/hip_bf16.h>

typedef unsigned long long u64;

#define KNMS 1000      // MAX_BOX_PRE_NMS (hardcoded in reference)
#define KP   1024      // padded stride for per-pair arrays
#define CAP  4096      // candidate capacity per pair
#define NBIN 8192      // radix-select histogram bins (score bits >> 18)
#define SLC  8         // A-dimension splits for hist/compact
#define FBN  8192      // final per-batch sort size (>= C*mb)
#define IOU_THR 0.5f

#define NEGINF __uint_as_float(0xFF800000u)

// ---------------------------------------------------------------------------
// helpers
// ---------------------------------------------------------------------------

// Find the histogram bin containing rank `rank` counting from the TOP.
__device__ __forceinline__ void find_cutoff(unsigned int* hist, int nbins,
    unsigned int* csum, int nthreads, int tid, unsigned int rank,
    unsigned int* s_bin, unsigned int* s_gt, unsigned int* s_total, int* s_all) {
  int chunk = nbins / nthreads;
  unsigned int cs = 0;
  int base = tid * chunk;
  for (int q = 0; q < chunk; q++) cs += hist[base + q];
  csum[tid] = cs;
  __syncthreads();
  if (tid == 0) {
    unsigned int total = 0;
    for (int ch = 0; ch < nthreads; ch++) total += csum[ch];
    *s_total = total;
    if (total <= rank) { *s_bin = 0u; *s_gt = 0u; *s_all = 1; }
    else {
      unsigned int acc = 0; int ch = nthreads - 1;
      while (acc + csum[ch] < rank) { acc += csum[ch]; ch--; }
      int bin = ch * chunk + chunk - 1;
      while (acc + hist[bin] < rank) { acc += hist[bin]; bin--; }
      *s_bin = (unsigned)bin; *s_gt = acc; *s_all = 0;
    }
  }
  __syncthreads();
}

// In-LDS bitonic sort, descending, 64-bit keys.
template<int N, int NT>
__device__ __forceinline__ void bitonic_desc(u64* a, int tid) {
  for (int k = 2; k <= N; k <<= 1) {
    for (int j = k >> 1; j > 0; j >>= 1) {
      for (int t = tid; t < N; t += NT) {
        int ixj = t ^ j;
        if (ixj > t) {
          u64 x = a[t], y = a[ixj];
          if (((t & k) == 0) ? (x < y) : (x > y)) { a[t] = y; a[ixj] = x; }
        }
      }
      __syncthreads();
    }
  }
}

// ---------------------------------------------------------------------------
// kernel 1: transpose classification [B,A,C] -> [B,C,A]  (C <= 127)
// ---------------------------------------------------------------------------
__global__ __launch_bounds__(256) void k_transpose(const float* __restrict__ src0,
    float* __restrict__ dst0, int A, int C) {
  __shared__ float tile[64 * 129];
  int b = blockIdx.y;
  int a0 = blockIdx.x * 64;
  const float* src = src0 + (size_t)b * A * C;
  float* dst = dst0 + (size_t)b * A * C;
  int st = C + 1;
  for (int idx = threadIdx.x; idx < 64 * C; idx += 256) {
    int al = idx / C, c = idx - al * C;
    int a = a0 + al;
    tile[al * st + c] = (a < A) ? src[(size_t)a * C + c] : 0.f;
  }
  __syncthreads();
  for (int idx = threadIdx.x; idx < 64 * C; idx += 256) {
    int c = idx >> 6, al = idx & 63;
    int a = a0 + al;
    if (a < A) dst[(size_t)c * A + a] = tile[al * st + c];
  }
}

// ---------------------------------------------------------------------------
// kernel 2a: per (pair, slice): LDS histogram of score bits>>18, merged to
// global hist via non-returning atomics (only ~32 nonzero bins/block).
// ---------------------------------------------------------------------------
__global__ __launch_bounds__(256) void k_hist(const float* __restrict__ cls,
    int transposed, const float* __restrict__ thr_p,
    unsigned int* __restrict__ ghist, int A, int C) {
  int pair = blockIdx.x, s = blockIdx.y, tid = threadIdx.x;
  int b = pair / C, c = pair - b * C;
  const float* col; int str;
  if (transposed) { col = cls + (size_t)pair * A; str = 1; }
  else            { col = cls + (size_t)b * A * C + c; str = C; }
  float thr = *thr_p;
  __shared__ unsigned int lh[NBIN];
  for (int i = tid; i < NBIN; i += 256) lh[i] = 0u;
  __syncthreads();
  bool vec = (str == 1) && ((A & 3) == 0);
  if (vec) {
    const float4* col4 = (const float4*)col;
    int A4 = A >> 2;
    int n4 = (A4 + SLC - 1) / SLC, i0 = s * n4, i1 = min(A4, i0 + n4);
    for (int i = i0 + tid; i < i1; i += 256) {
      float4 v = col4[i];
      float vv[4] = {v.x, v.y, v.z, v.w};
#pragma unroll
      for (int q = 0; q < 4; q++)
        if (vv[q] > thr) atomicAdd(&lh[__float_as_uint(vv[q]) >> 18], 1u);
    }
  } else {
    int nE = (A + SLC - 1) / SLC, a0 = s * nE, a1 = min(A, a0 + nE);
    for (int a = a0 + tid; a < a1; a += 256) {
      float sv = col[(size_t)a * str];
      if (sv > thr) atomicAdd(&lh[__float_as_uint(sv) >> 18], 1u);
    }
  }
  __syncthreads();
  unsigned int* gh = ghist + (size_t)pair * NBIN;
  for (int i = tid; i < NBIN; i += 256) {
    unsigned v = lh[i];
    if (v) atomicAdd(&gh[i], v);
  }
}

// ---------------------------------------------------------------------------
// kernel 2b: per pair: find cutoff bin for rank KNMS. cut=0 means take-all.
// Margin: bin width 2^-18 -> boundary-bin count ~1.6K for this workload;
// takers <= ~2.6K << CAP=4096.
// ---------------------------------------------------------------------------
__global__ __launch_bounds__(512) void k_cutoff(const unsigned int* __restrict__ ghist,
    unsigned int* __restrict__ cut) {
  int pair = blockIdx.x, tid = threadIdx.x;
  __shared__ unsigned int lh[NBIN];
  __shared__ unsigned int csum[512];
  __shared__ unsigned int s_b1, s_gt, s_tot;
  __shared__ int s_all;
  const unsigned int* gh = ghist + (size_t)pair * NBIN;
  for (int i = tid; i < NBIN; i += 512) lh[i] = gh[i];
  __syncthreads();
  find_cutoff(lh, NBIN, csum, 512, tid, KNMS, &s_b1, &s_gt, &s_tot, &s_all);
  if (tid == 0) cut[pair] = s_all ? 0u : s_b1;
}

// ---------------------------------------------------------------------------
// kernel 2c: per (pair, slice): compact keys with bin >= cut.
// LDS staging: one LDS atomic per wave-ballot for in-block positions, ONE
// returning global atomic per BLOCK (was: per wave-ballot -> ~1100 serialized
// same-address round-trips per pair = the round-2 330us pathology), then a
// bulk coalesced LDS->global dump. Inter-block order is nondeterministic but
// keys are unique and fully sorted later -> deterministic output.
// key = (score_bits << 32) | ~anchor_index (stable: low index wins ties)
// ---------------------------------------------------------------------------
__global__ __launch_bounds__(256) void k_compact(const float* __restrict__ cls,
    int transposed, const float* __restrict__ thr_p,
    const unsigned int* __restrict__ cut, int* __restrict__ gcnt,
    u64* __restrict__ gcand, int A, int C) {
  int pair = blockIdx.x, s = blockIdx.y, tid = threadIdx.x;
  int b = pair / C, c = pair - b * C;
  const float* col; int str;
  if (transposed) { col = cls + (size_t)pair * A; str = 1; }
  else            { col = cls + (size_t)b * A * C + c; str = C; }
  float thr = *thr_p;
  unsigned b1 = cut[pair];

  __shared__ u64 sbuf[CAP];
  __shared__ int s_n, s_base;
  if (tid == 0) s_n = 0;
  __syncthreads();

  int lane = tid & 63;
  auto stage = [&](u64 key, bool take) {
    u64 m = __ballot(take);
    if (!m) return;
    int ldr = __ffsll((long long)m) - 1;
    int base = 0;
    if (lane == ldr) base = atomicAdd(&s_n, (int)__popcll(m));
    base = __shfl(base, ldr);
    if (take) {
      int pos = base + (int)__popcll(m & ((1ull << lane) - 1ull));
      if (pos < CAP) sbuf[pos] = key;
    }
  };

  bool vec = (str == 1) && ((A & 3) == 0);
  if (vec) {
    const float4* col4 = (const float4*)col;
    int A4 = A >> 2;
    int n4 = (A4 + SLC - 1) / SLC, i0 = s * n4, i1 = min(A4, i0 + n4);
    for (int i = i0 + tid; i < i1; i += 256) {
      float4 v = col4[i];
      float vv[4] = {v.x, v.y, v.z, v.w};
#pragma unroll
      for (int q = 0; q < 4; q++) {
        float sv = vv[q];
        unsigned bits = __float_as_uint(sv);
        bool take = (sv > thr) && ((bits >> 18) >= b1);
        u64 key = ((u64)bits << 32) | (unsigned)(~(unsigned)(i * 4 + q));
        stage(key, take);
      }
    }
  } else {
    int nE = (A + SLC - 1) / SLC, a0 = s * nE, a1 = min(A, a0 + nE);
    for (int a = a0 + tid; a < a1; a += 256) {
      float sv = col[(size_t)a * str];
      unsigned bits = __float_as_uint(sv);
      bool take = (sv > thr) && ((bits >> 18) >= b1);
      u64 key = ((u64)bits << 32) | (unsigned)(~(unsigned)a);
      stage(key, take);
    }
  }
  __syncthreads();
  int n = s_n < CAP ? s_n : CAP;
  if (tid == 0) s_base = atomicAdd(&gcnt[pair], s_n);  // true total (unclamped)
  __syncthreads();
  int base = s_base;
  u64* dst = gcand + (size_t)pair * CAP;
  for (int t = tid; t < n; t += 256) {
    int pos = base + t;
    if (pos < CAP) dst[pos] = sbuf[t];
  }
}

// ---------------------------------------------------------------------------
// kernel 2d: per pair: sort candidates desc, gather boxes, write sorted arrays
// ---------------------------------------------------------------------------
__global__ __launch_bounds__(1024) void k_sortpairs(const u64* __restrict__ gcand,
    const int* __restrict__ gcnt, const float* __restrict__ tanch,
    float* __restrict__ scores_s, float* __restrict__ boxes_s,
    float* __restrict__ area_s, int* __restrict__ cnt_s, int A, int C) {
  int pair = blockIdx.x, tid = threadIdx.x;
  int b = pair / C;
  __shared__ u64 cand[CAP];
  int nc = gcnt[pair];
  int n = nc < CAP ? nc : CAP;
  for (int t = tid; t < CAP; t += 1024)
    cand[t] = (t < n) ? gcand[(size_t)pair * CAP + t] : 0ull;
  __syncthreads();
  bitonic_desc<CAP, 1024>(cand, tid);
  int n_valid = nc < KNMS ? nc : KNMS;
  for (int k = tid; k < KNMS; k += 1024) {
    u64 key = cand[k];
    float sc; float4 bx; float ar;
    if (k < n_valid && key != 0ull) {
      sc = __uint_as_float((unsigned)(key >> 32));
      unsigned a = ~(unsigned)key;
      bx = ((const float4*)tanch)[(size_t)b * A + a];
      ar = (bx.z - bx.x) * (bx.w - bx.y);
    } else {
      sc = NEGINF; bx = make_float4(0.f, 0.f, 0.f, 0.f); ar = 0.f;
    }
    scores_s[(size_t)pair * KP + k] = sc;
    ((float4*)boxes_s)[(size_t)pair * KP + k] = bx;
    area_s[(size_t)pair * KP + k] = ar;
  }
  if (tid == 0) cnt_s[pair] = n_valid;
}

// ---------------------------------------------------------------------------
// kernel 3: suppression matrix. Bit-exact vs reference:
// fl(inter/uni) > 0.5  <=>  2*inter > uni*(1+2^-24), exact in f64
// (24-bit x 25-bit mantissas fit 53 bits; midpoint ties round to even 0.5;
//  inter=uni=0 -> NaN -> false on both sides; uni<0 impossible).
// ---------------------------------------------------------------------------
__global__ __launch_bounds__(256) void k_iou(const float* __restrict__ boxes_s,
    const float* __restrict__ area_s, const int* __restrict__ cnt_s,
    u64* __restrict__ mat) {
  int pair = blockIdx.x, w = blockIdx.y;
  int cnt = cnt_s[pair];
  int lim = (w + 1) * 64; if (lim > KNMS) lim = KNMS;  // rows needed: i < w*64+63
  __shared__ float4 sbox[KNMS];
  __shared__ float sarea[KNMS];
  for (int i = threadIdx.x; i < lim; i += 256) {
    sbox[i] = ((const float4*)boxes_s)[(size_t)pair * KP + i];
    sarea[i] = area_s[(size_t)pair * KP + i];
  }
  __syncthreads();
  int lane = threadIdx.x & 63, wv = threadIdx.x >> 6;
  int j = w * 64 + lane;
  bool jok = j < KNMS;
  float4 bj = (jok && j < lim) ? sbox[j] : make_float4(0.f, 0.f, 0.f, 0.f);
  float aj = (jok && j < lim) ? sarea[j] : 0.f;
  u64* orow = mat + (size_t)pair * KP * 16 + w;
  int rowLim = cnt < (w * 64 + 63) ? cnt : (w * 64 + 63);
  for (int i = wv; i < rowLim; i += 4) {
    float4 bi = sbox[i]; float ai = sarea[i];
    float ltx = fmaxf(bi.x, bj.x), lty = fmaxf(bi.y, bj.y);
    float rbx = fminf(bi.z, bj.z), rby = fminf(bi.w, bj.w);
    float ww = fmaxf(rbx - ltx, 0.f), hh = fmaxf(rby - lty, 0.f);
    float inter = ww * hh;
    float uni = (ai + aj) - inter;
    bool sup = jok && (j > i) &&
               ((double)inter * 2.0 > (double)uni * (1.0 + 0x1p-24));
    u64 word = __ballot(sup);
    if (lane == 0) orow[(size_t)i * 16] = word;
  }
  for (int i = rowLim + wv; i < cnt; i += 4)
    if (lane == 0) orow[(size_t)i * 16] = 0ull;
}

// ---------------------------------------------------------------------------
// kernel 4: serial greedy scan. 1 wave per pair; lanes 0..15 own keep-words.
// ---------------------------------------------------------------------------
__global__ __launch_bounds__(64) void k_scan(const u64* __restrict__ mat,
    const int* __restrict__ cnt_s, u64* __restrict__ keep_out) {
  int pair = blockIdx.x;
  int lane = threadIdx.x;
  int cnt = cnt_s[pair];
  const u64* m = mat + (size_t)pair * KP * 16;
  u64 keepw = 0ull;
  if (lane < 16) {
    int nb = cnt - lane * 64;
    nb = nb < 0 ? 0 : (nb > 64 ? 64 : nb);
    keepw = (nb >= 64) ? ~0ull : ((nb > 0) ? ((1ull << nb) - 1ull) : 0ull);
  }
  bool ld = lane < 16;
  u64 cur[16], nxt[16];
#pragma unroll
  for (int r = 0; r < 16; r++) cur[r] = (ld && r < cnt) ? m[(size_t)r * 16 + lane] : 0ull;
  for (int g = 0; g < cnt; g += 16) {
#pragma unroll
    for (int r = 0; r < 16; r++) {
      int i = g + 16 + r;
      nxt[r] = (ld && i < cnt) ? m[(size_t)i * 16 + lane] : 0ull;
    }
#pragma unroll
    for (int r = 0; r < 16; r++) {
      int i = g + r;
      if (i < cnt) {
        u64 kw = __shfl(keepw, i >> 6);
        if ((kw >> (i & 63)) & 1ull) keepw &= ~cur[r];
      }
      cur[r] = nxt[r];
    }
  }
  if (lane < 16) keep_out[pair * 16 + lane] = keepw;
}

// ---------------------------------------------------------------------------
// kernel 5a: per pair: emit top-min(mb,kept) kept keys (scores_s is sorted,
// so the first set bits ARE the best). 1 wave per pair.
// key = (score_bits << 32) | ~(c*KNMS + k)
// ---------------------------------------------------------------------------
__global__ __launch_bounds__(64) void k_fa(const u64* __restrict__ keepm,
    const float* __restrict__ scores_s, u64* __restrict__ fa, int C, int mb) {
  int pair = blockIdx.x;
  int lane = threadIdx.x;
  int c = pair % C;
  u64 kw = (lane < 16) ? keepm[pair * 16 + lane] : 0ull;
  int pc = __popcll(kw);
  int scan = pc;
  for (int d = 1; d < 16; d <<= 1) {
    int o = __shfl_up(scan, d);
    if (lane >= d) scan += o;
  }
  int base = scan - pc;
  int total = __shfl(scan, 15);
  if (lane < 16) {
    u64 m = kw; int r = base;
    while (m && r < mb) {
      int bit = __ffsll((long long)m) - 1; m &= m - 1;
      int k = lane * 64 + bit;
      float s = scores_s[(size_t)pair * KP + k];
      fa[(size_t)pair * mb + r] =
          ((u64)__float_as_uint(s) << 32) | (unsigned)(~(unsigned)(c * KNMS + k));
      r++;
    }
  }
  int start = total < mb ? total : mb;
  for (int r = start + lane; r < mb; r += 64) fa[(size_t)pair * mb + r] = 0ull;
}

// ---------------------------------------------------------------------------
// kernel 5b: per batch: sort C*mb candidate keys desc, write outputs.
// ---------------------------------------------------------------------------
__global__ __launch_bounds__(1024) void k_fb(const u64* __restrict__ fa,
    const float* __restrict__ boxes_s, float* __restrict__ out,
    int B, int C, int mb) {
  int b = blockIdx.x, tid = threadIdx.x;
  __shared__ u64 cand[FBN];
  int nk = C * mb; if (nk > FBN) nk = FBN;
  const u64* src = fa + (size_t)b * C * mb;
  for (int i = tid; i < FBN; i += 1024) cand[i] = (i < nk) ? src[i] : 0ull;
  __syncthreads();
  bitonic_desc<FBN, 1024>(cand, tid);
  for (int k = tid; k < mb; k += 1024) {
    u64 key = cand[k];
    float4 bx = make_float4(0.f, 0.f, 0.f, 0.f);
    float sc = 0.f, cf = -1.f;
    if (key != 0ull) {
      sc = __uint_as_float((unsigned)(key >> 32));
      unsigned flat = ~(unsigned)key;
      int c = flat / KNMS;
      int kk = flat - c * KNMS;
      bx = ((const float4*)boxes_s)[(size_t)(b * C + c) * KP + kk];
      cf = (float)c;
    }
    size_t ro = (size_t)(b * mb + k) * 4;
    out[ro + 0] = bx.x; out[ro + 1] = bx.y; out[ro + 2] = bx.z; out[ro + 3] = bx.w;
    out[(size_t)B * mb * 4 + b * mb + k] = sc;
    out[(size_t)B * mb * 5 + b * mb + k] = cf;
  }
}

// ---------------------------------------------------------------------------
extern "C" void kernel_launch(void* const* d_in, const int* in_sizes, int n_in,
                              void* d_out, int out_size, void* d_ws, size_t ws_size,
                              hipStream_t stream) {
  const float* classification = (const float*)d_in[3];
  const float* tanch = (const float*)d_in[4];
  const float* thr_p = (const float*)d_in[5];

  int B = in_sizes[0] / (3 * 64 * 64);
  if (B <= 0) B = 4;
  long long BA = (long long)in_sizes[4] / 4;
  int A = (int)(BA / B);
  int C = (int)((long long)in_sizes[3] / BA);
  int NP = B * C;
  int mb = out_size / (B * 6);

  auto rsz = [](size_t x) { return (x + 255) & ~(size_t)255; };
  size_t clsT_bytes = rsz((size_t)NP * A * 4);
  size_t rest = rsz((size_t)NP * KP * 4)       // scores
              + rsz((size_t)NP * KP * 16)      // boxes
              + rsz((size_t)NP * KP * 4)       // areas
              + rsz((size_t)NP * 4)            // counts
              + rsz((size_t)NP * KP * 16 * 8)  // suppression matrix (+aliases)
              + rsz((size_t)NP * 16 * 8);      // keep masks
  int use_t = (C <= 127 && ws_size >= rest + clsT_bytes) ? 1 : 0;

  size_t off = 0;
  auto take = [&](size_t bytes) {
    void* p = (char*)d_ws + off;
    off += rsz(bytes);
    return p;
  };
  float* clsT = nullptr;
  if (use_t) clsT = (float*)take((size_t)NP * A * 4);
  float* scores_s = (float*)take((size_t)NP * KP * 4);
  float* boxes_s  = (float*)take((size_t)NP * KP * 16);
  float* area_s   = (float*)take((size_t)NP * KP * 4);
  int*   cnt_s    = (int*)take((size_t)NP * 4);
  u64*   mat      = (u64*)take((size_t)NP * KP * 16 * 8);
  u64*   keepm    = (u64*)take((size_t)NP * 16 * 8);

  // Alias selection/final scratch into the mat region (disjoint lifetimes:
  // ghist/gcnt/cut/gcand die before k_iou writes mat; fa is written after
  // k_scan's last read of mat). Total aliased ~21.2 MB <= 41.9 MB.
  char* matc = (char*)mat;
  size_t ao = 0;
  unsigned int* ghist = (unsigned int*)(matc + ao); ao += rsz((size_t)NP * NBIN * 4);
  int* gcnt           = (int*)(matc + ao);          ao += rsz((size_t)NP * 4);
  unsigned int* cut   = (unsigned int*)(matc + ao); ao += rsz((size_t)NP * 4);
  u64* gcand          = (u64*)(matc + ao);          ao += rsz((size_t)NP * CAP * 8);
  u64* fa             = (u64*)(matc + ao);          ao += rsz((size_t)NP * mb * 8);

  hipMemsetAsync(ghist, 0, (size_t)NP * NBIN * 4, stream);
  hipMemsetAsync(gcnt, 0, (size_t)NP * 4, stream);

  if (use_t)
    k_transpose<<<dim3((A + 63) / 64, B), 256, 0, stream>>>(classification, clsT, A, C);
  const float* cl = use_t ? clsT : classification;
  k_hist<<<dim3(NP, SLC), 256, 0, stream>>>(cl, use_t, thr_p, ghist, A, C);
  k_cutoff<<<NP, 512, 0, stream>>>(ghist, cut);
  k_compact<<<dim3(NP, SLC), 256, 0, stream>>>(cl, use_t, thr_p, cut, gcnt, gcand, A, C);
  k_sortpairs<<<NP, 1024, 0, stream>>>(gcand, gcnt, tanch, scores_s, boxes_s, area_s, cnt_s, A, C);
  k_iou<<<dim3(NP, 16), 256, 0, stream>>>(boxes_s, area_s, cnt_s, mat);
  k_scan<<<NP, 64, 0, stream>>>(mat, cnt_s, keepm);
  k_fa<<<NP, 64, 0, stream>>>(keepm, scores_s, fa, C, mb);
  k_fb<<<B, 1024, 0, stream>>>(fa, boxes_s, (float*)d_out, B, C, mb);
}